// Round 11
// baseline (110.132 us; speedup 1.0000x reference)
//
#include <hip/hip_runtime.h>
#include <cstdint>
#include <cstddef>

#define BB 4
#define CC 256
#define NN 4096
#define CO 32

typedef __attribute__((ext_vector_type(8))) short bf8;
typedef __attribute__((ext_vector_type(4))) float f4;
typedef __attribute__((ext_vector_type(16))) float f16f;
typedef __attribute__((ext_vector_type(2))) unsigned int u32x2;

#define AS1 __attribute__((address_space(1)))
#define AS3 __attribute__((address_space(3)))

__device__ __forceinline__ unsigned short f2bf(float f) {
    union { float f; unsigned int u; } c; c.f = f;
    unsigned int r = c.u + 0x7FFFu + ((c.u >> 16) & 1u);
    return (unsigned short)(r >> 16);
}
__device__ __forceinline__ float bf2f(unsigned short b) {
    union { unsigned int u; float f; } c; c.u = ((unsigned int)b) << 16;
    return c.f;
}
__device__ __forceinline__ unsigned int cvt_pk_bf16(float a, float b) {
    unsigned int r;
    asm("v_cvt_pk_bf16_f32 %0, %1, %2" : "=v"(r) : "v"(a), "v"(b));
    return r;
}

// ---------------- kernel 1: fused prep (transpose + QK-proj + V-proj) -------
__global__ __launch_bounds__(512, 2) void k_prep(
        const float* __restrict__ x,
        const float* __restrict__ wq, const float* __restrict__ bq,
        const float* __restrict__ wk, const float* __restrict__ bk,
        const float* __restrict__ wv, const float* __restrict__ bv,
        unsigned short* __restrict__ q_hi, unsigned short* __restrict__ q_lo,
        unsigned short* __restrict__ k_hi, unsigned short* __restrict__ k_lo,
        unsigned short* __restrict__ vws) {
    __shared__ float xT[64 * 256];   // (i,c) at i*256 + ((c>>2)^(i&7))*4 + (c&3)
    int blk = blockIdx.x;
    int it = blk & 63, b = blk >> 6;
    int i0 = it * 64;
    int tid = threadIdx.x, w = tid >> 6, lane = tid & 63;
    int lr = lane & 15, lg = lane >> 4;

    // phase 1: load + swizzled transpose
    {
        const float* xp = x + (size_t)b * CC * NN + i0;
        int cl = tid >> 4;            // 0..31
        int il = (tid & 15) * 4;      // 0..60
#pragma unroll
        for (int pass = 0; pass < 8; ++pass) {
            int c = pass * 32 + cl;
            f4 v = *(const f4*)(xp + (size_t)c * NN + il);
#pragma unroll
            for (int jj = 0; jj < 4; ++jj) {
                int i = il + jj;
                xT[i * 256 + (((c >> 2) ^ (i & 7)) << 2) + (c & 3)] = v[jj];
            }
        }
    }
    __syncthreads();

    if (w < 4) {
        // ---- Q/K projection, wave w -> local i rows [w*16, w*16+16) ----
        f4 acc[4] = {};
        for (int ks = 0; ks < 8; ++ks) {
            int i = w * 16 + lr;
            int kc = ks * 32 + lg * 8;
            f4 xa = *(const f4*)&xT[i * 256 + (((kc >> 2) ^ (i & 7)) << 2)];
            f4 xb = *(const f4*)&xT[i * 256 + ((((kc >> 2) + 1) ^ (i & 7)) << 2)];
            bf8 ahi, alo;
#pragma unroll
            for (int e = 0; e < 8; ++e) {
                float f = (e < 4) ? xa[e] : xb[e - 4];
                unsigned short hh = f2bf(f);
                ahi[e] = (short)hh;
                alo[e] = (short)f2bf(f - bf2f(hh));
            }
#pragma unroll
            for (int u = 0; u < 4; ++u) {
                int o = u * 16 + lr;
                const float* wrow = (u < 2) ? (wq + (size_t)o * CC)
                                            : (wk + (size_t)(o - 32) * CC);
                bf8 bhi, blo;
#pragma unroll
                for (int e = 0; e < 8; ++e) {
                    float wvv = wrow[ks * 32 + lg * 8 + e];
                    unsigned short hh = f2bf(wvv);
                    bhi[e] = (short)hh;
                    blo[e] = (short)f2bf(wvv - bf2f(hh));
                }
                acc[u] = __builtin_amdgcn_mfma_f32_16x16x32_bf16(alo, bhi, acc[u], 0, 0, 0);
                acc[u] = __builtin_amdgcn_mfma_f32_16x16x32_bf16(ahi, blo, acc[u], 0, 0, 0);
                acc[u] = __builtin_amdgcn_mfma_f32_16x16x32_bf16(ahi, bhi, acc[u], 0, 0, 0);
            }
        }
#pragma unroll
        for (int u = 0; u < 4; ++u) {
            int o = u * 16 + lr;
            float bias = (u < 2) ? bq[o] : bk[o - 32];
#pragma unroll
            for (int r = 0; r < 4; ++r) {
                int i = i0 + w * 16 + lg * 4 + r;
                float v = acc[u][r] + bias;
                unsigned short hh = f2bf(v);
                unsigned short ll = f2bf(v - bf2f(hh));
                if (u < 2) {
                    size_t off = ((size_t)b * NN + i) * CO + o;
                    q_hi[off] = hh; q_lo[off] = ll;
                } else {
                    size_t off = ((size_t)b * NN + i) * CO + (o - 32);
                    k_hi[off] = hh; k_lo[off] = ll;
                }
            }
        }
    } else {
        // ---- V projection, wave (w-4) -> c rows [(w-4)*64, +64) ----
        int cb = (w - 4) * 64;
        f4 acc[4][4];   // [u c-sub][t i-sub]
#pragma unroll
        for (int u = 0; u < 4; ++u) {
            f4 bias4;
#pragma unroll
            for (int r = 0; r < 4; ++r) bias4[r] = bv[cb + u * 16 + lg * 4 + r];
#pragma unroll
            for (int t = 0; t < 4; ++t) acc[u][t] = bias4;
        }
        for (int ks = 0; ks < 8; ++ks) {
            bf8 bfr[4];
#pragma unroll
            for (int t = 0; t < 4; ++t) {
                int i = t * 16 + lr;
                int kc = ks * 32 + lg * 8;
                f4 xa = *(const f4*)&xT[i * 256 + (((kc >> 2) ^ (i & 7)) << 2)];
                f4 xb = *(const f4*)&xT[i * 256 + ((((kc >> 2) + 1) ^ (i & 7)) << 2)];
#pragma unroll
                for (int e = 0; e < 8; ++e)
                    bfr[t][e] = (short)f2bf((e < 4) ? xa[e] : xb[e - 4]);
            }
#pragma unroll
            for (int u = 0; u < 4; ++u) {
                const float* wrow = wv + (size_t)(cb + u * 16 + lr) * CC + ks * 32 + lg * 8;
                bf8 afr;
#pragma unroll
                for (int e = 0; e < 8; ++e) afr[e] = (short)f2bf(wrow[e]);
#pragma unroll
                for (int t = 0; t < 4; ++t)
                    acc[u][t] = __builtin_amdgcn_mfma_f32_16x16x32_bf16(afr, bfr[t], acc[u][t], 0, 0, 0);
            }
        }
#pragma unroll
        for (int u = 0; u < 4; ++u)
#pragma unroll
            for (int t = 0; t < 4; ++t)
#pragma unroll
                for (int r = 0; r < 4; ++r) {
                    int c = cb + u * 16 + lg * 4 + r;
                    vws[((size_t)b * CC + c) * NN + i0 + t * 16 + lr] = f2bf(acc[u][t][r]);
                }
    }
}

// ---------------- kernel 2: flash attention + residual ----------------
// 256 blocks (1/CU), 8 waves. Block = (batch, 64q, ALL 256c).
// Single-barrier software pipeline, window jt:
//   barrier(vmcnt0+lgkm0) ; stage V(jt+1)->Vt[(jt+1)&1], K(jt+2)->K2[jt&1]
//   S(jt+1): K from K2[(jt+1)&1], swapped QK^T 16x16 split, in-reg exp,
//            P -> Pt[(jt+1)&1]   (roles a=w&3 qtile, h=w>>2 jhalf; no dup)
//   PV(jt):  Pt[jt&1] x Vt[jt&1], 32x32x16; wave owns 64c x 32q
//            (qg=w>>2, cw=w&3) -> P over-read 4x (was 8x), DS ops -40%.
// All cross-window deps barrier-separated; stages get a full window of
// latency cover before their vmcnt(0) drain.
__global__ __launch_bounds__(512, 1) void k_attn(
        const unsigned short* __restrict__ q_hi, const unsigned short* __restrict__ q_lo,
        const unsigned short* __restrict__ k_hi, const unsigned short* __restrict__ k_lo,
        const unsigned short* __restrict__ vws,
        const float* __restrict__ x, float* __restrict__ out) {
    __shared__ __align__(16) unsigned short Vt[2][16384];  // [p][c256][slot8][8] 32KB each
    __shared__ __align__(16) unsigned short K2[2][4096];   // [p][j64][slot8][8] hi0-3/lo4-7
    __shared__ __align__(16) unsigned short Pt[2][4096];   // [p][q64][slot8][8]
    __shared__ float lsum_s[2][64];                        // [jh][q]

    int m = blockIdx.x;
    int xcd = m & 7;                 // XCD pair {2b,2b+1} serves batch b
    int b = xcd >> 1;
    int qblk = ((m >> 3) << 1) + (xcd & 1);   // 0..63
    int i0 = qblk * 64;
    int tid = threadIdx.x, w = tid >> 6, lane = tid & 63;
    int lr = lane & 15, lg = lane >> 4, lr7 = lr & 7;
    int a = w & 3, h = w >> 2;       // S roles: q-tile a (16q), j-half h (32j)
    int l31 = lane & 31, hh = lane >> 5;
    int cw = w & 3, qg = w >> 2;     // PV roles: c-slice cw (64c), q-half qg (32q)

    // Q fragments (B-operand): lane holds Q[q = i0+a*16+lr][d = lg*8+e]
    bf8 qfh, qfl;
    {
        size_t off = ((size_t)b * NN + i0 + a * 16 + lr) * CO + lg * 8;
        qfh = *(const bf8*)(q_hi + off);
        qfl = *(const bf8*)(q_lo + off);
    }

    // stage sources (pre-swizzled involution: phys slot sl holds chunk sl^(row&7))
    int l3 = lane >> 3, sl = lane & 7;
    int us = sl ^ l3;
    const unsigned short* kbase = (us < 4) ? (k_hi + (size_t)b * NN * CO + us * 8)
                                           : (k_lo + (size_t)b * NN * CO + (us - 4) * 8);
    const unsigned short* ksrc = kbase + (size_t)(w * 8 + l3) * CO;
    const unsigned short* vsrc = vws + ((size_t)b * CC + w * 32 + l3) * NN + us * 8;

    auto stageK = [&](int jt, int p) {
        int j0 = ((jt < 64) ? jt : 63) * 64;
        __builtin_amdgcn_global_load_lds((const AS1 void*)(ksrc + (size_t)j0 * CO),
            (AS3 void*)(&K2[p][(w * 8) * 64]), 16, 0, 0);
    };
    auto stageV = [&](int jt, int p) {
        int j0 = ((jt < 64) ? jt : 63) * 64;
#pragma unroll
        for (int n = 0; n < 4; ++n) {
            __builtin_amdgcn_global_load_lds((const AS1 void*)(vsrc + (size_t)(n * 8) * NN + j0),
                (AS3 void*)(&Vt[p][(w * 32 + n * 8) * 64]), 16, 0, 0);
        }
    };

    f16f acc0 = {}, acc1 = {};   // O^T: cols q = qg*32+l31; rows c per reg
    float lsum = 0.f;

    // S(js): reads K2[js&1], writes Pt[js&1]; covers (q-tile a) x (j-half h)
    auto S_phase = [&](int js) {
        int pk = js & 1;
#pragma unroll
        for (int t = 0; t < 2; ++t) {
            int jl = h * 32 + t * 16 + lr;
            const unsigned short* Kp = &K2[pk][jl * 64];
            bf8 kfh = *(const bf8*)(Kp + ((lg ^ lr7)) * 8);
            bf8 kfl = *(const bf8*)(Kp + (((4 | lg) ^ lr7)) * 8);
            f4 s = {};
            s = __builtin_amdgcn_mfma_f32_16x16x32_bf16(kfh, qfl, s, 0, 0, 0);
            s = __builtin_amdgcn_mfma_f32_16x16x32_bf16(kfl, qfh, s, 0, 0, 0);
            s = __builtin_amdgcn_mfma_f32_16x16x32_bf16(kfh, qfh, s, 0, 0, 0);
            float e0 = __expf(s[0]), e1 = __expf(s[1]), e2 = __expf(s[2]), e3 = __expf(s[3]);
            lsum += (e0 + e1) + (e2 + e3);
            u32x2 d;
            d[0] = cvt_pk_bf16(e0, e1);
            d[1] = cvt_pk_bf16(e2, e3);
            int row = a * 16 + lr;
            int swz = (row ^ (row >> 3)) & 7;
            int slot = (h * 4 + t * 2 + (lg >> 1)) ^ swz;
            *(u32x2*)&Pt[pk][row * 64 + slot * 8 + (lg & 1) * 4] = d;
        }
    };
    // PV(jt): acc += V(A) x P(B), 32x32x16; wave covers 64c x 32q, full 64 j
    auto PV_phase = [&](int jt) {
        int pv = jt & 1;
        int prow = qg * 32 + l31;
        int pswz = (prow ^ (prow >> 3)) & 7;
        const unsigned short* Pr  = &Pt[pv][prow * 64];
        const unsigned short* Vr0 = &Vt[pv][(cw * 64 + l31) * 64];
        const unsigned short* Vr1 = &Vt[pv][(cw * 64 + 32 + l31) * 64];
        int vswz = l31 & 7;
#pragma unroll
        for (int kc = 0; kc < 4; ++kc) {
            bf8 pb = *(const bf8*)(Pr  + (((kc * 2 + hh) ^ pswz)) * 8);
            bf8 v0 = *(const bf8*)(Vr0 + (((kc * 2 + hh) ^ vswz)) * 8);
            bf8 v1 = *(const bf8*)(Vr1 + (((kc * 2 + hh) ^ vswz)) * 8);
            acc0 = __builtin_amdgcn_mfma_f32_32x32x16_bf16(v0, pb, acc0, 0, 0, 0);
            acc1 = __builtin_amdgcn_mfma_f32_32x32x16_bf16(v1, pb, acc1, 0, 0, 0);
        }
    };

    // prologue: V(0), K(0) staged; drain; K(1) staged under S(0)'s compute
    stageK(0, 0);
    stageV(0, 0);
    __builtin_amdgcn_sched_barrier(0);
    asm volatile("s_waitcnt vmcnt(0) lgkmcnt(0)" ::: "memory");
    __builtin_amdgcn_s_barrier();
    __builtin_amdgcn_sched_barrier(0);
    stageK(1, 1);
    S_phase(0);

    for (int jt = 0; jt < 64; ++jt) {
        // ---- ONE barrier per window ----
        __builtin_amdgcn_sched_barrier(0);
        asm volatile("s_waitcnt vmcnt(0) lgkmcnt(0)" ::: "memory");
        __builtin_amdgcn_s_barrier();
        __builtin_amdgcn_sched_barrier(0);
        // stages issued first: a full window of latency cover before drain
        stageV(jt + 1, (jt + 1) & 1);
        stageK(jt + 2, jt & 1);
        if (jt < 63) S_phase(jt + 1);
        __builtin_amdgcn_s_setprio(1);
        PV_phase(jt);
        __builtin_amdgcn_s_setprio(0);
    }

    // denominator: lane covered q=a*16+lr, j-half h; reduce over lg groups
    lsum += __shfl_xor(lsum, 16, 64);
    lsum += __shfl_xor(lsum, 32, 64);
    if (lane < 16) lsum_s[h][a * 16 + lane] = lsum;
    __syncthreads();

    // epilogue: O^T * linv + residual (32x32 C/D: col q = l31, row c per reg)
    int qloc = qg * 32 + l31;
    float linv = 1.0f / (lsum_s[0][qloc] + lsum_s[1][qloc]);
    int iq = i0 + qloc;
#pragma unroll
    for (int r = 0; r < 16; ++r) {
        int c0 = cw * 64 + (r & 3) + 8 * (r >> 2) + 4 * hh;
        size_t off0 = ((size_t)(b * CC + c0)) * NN + iq;
        out[off0] = acc0[r] * linv + x[off0];
        size_t off1 = ((size_t)(b * CC + c0 + 32)) * NN + iq;
        out[off1] = acc1[r] * linv + x[off1];
    }
}

extern "C" void kernel_launch(void* const* d_in, const int* in_sizes, int n_in,
                              void* d_out, int out_size, void* d_ws, size_t ws_size,
                              hipStream_t stream) {
    const float* x  = (const float*)d_in[0];
    const float* wq = (const float*)d_in[1];
    const float* bq = (const float*)d_in[2];
    const float* wk = (const float*)d_in[3];
    const float* bk = (const float*)d_in[4];
    const float* wv = (const float*)d_in[5];
    const float* bv = (const float*)d_in[6];
    float* out = (float*)d_out;
    char* ws = (char*)d_ws;
    // ws: qh 1MB | ql 1MB | kh 1MB | kl 1MB | v 8MB
    unsigned short* qh = (unsigned short*)(ws);
    unsigned short* ql = (unsigned short*)(ws + 1048576);
    unsigned short* kh = (unsigned short*)(ws + 2097152);
    unsigned short* kl = (unsigned short*)(ws + 3145728);
    unsigned short* vv = (unsigned short*)(ws + 4194304);

    hipLaunchKernelGGL(k_prep, dim3(256), dim3(512), 0, stream,
                       x, wq, bq, wk, bk, wv, bv, qh, ql, kh, kl, vv);
    hipLaunchKernelGGL(k_attn, dim3(256), dim3(512), 0, stream,
                       qh, ql, kh, kl, vv, x, out);
}